// Round 3
// baseline (243.344 us; speedup 1.0000x reference)
//
#include <hip/hip_runtime.h>
#include <math.h>

#define NCLS 16
#define TILE 32
#define PAD  36      // floats per LDS row: 144 B -> rows 16B-aligned (b128 reads), +4 bank shift
#define NB   2048
#define PIXB 32      // pixels per norm block (8 d-lanes x 32 pixels = 256 threads)

struct Ctl {
    int   counts[NCLS];
    int   starts[NCLS + 1];
    int   tpc[NCLS];          // tiles per class dimension = ceil(n/TILE)
    int   pairBase[NCLS + 1]; // prefix sum of tpc^2
    int   done;               // last-block-done counter for fused finalize
    float classSum[NCLS];
};

// ---------------- Kernel 1: norms (parallel over pixel AND dim) + ctl -------
// gt is SORTED -> class boundaries via binary search; contiguous segments == classes.
__global__ __launch_bounds__(256) void prep_kernel(
    const float* __restrict__ P, const float* __restrict__ T,
    const int* __restrict__ gt, int V, int D,
    Ctl* __restrict__ ctl,
    float* __restrict__ normP, float* __restrict__ normT,
    int nbNorm) {
    const int b = blockIdx.x;
    const int t = threadIdx.x;
    if (b < nbNorm) {
        // 32 pixels/block, 8 dim-lanes/pixel: lanes with same dl read
        // consecutive v for each d -> coalesced 128 B per wave-quarter.
        __shared__ float pP[8][PIXB], pT[8][PIXB];
        const int pix = t & (PIXB - 1);
        const int dl  = t >> 5;           // 0..7
        const int v   = b * PIXB + pix;
        float np = 0.f, nt = 0.f;
        if (v < V) {
            for (int d = dl; d < D; d += 8) {
                float x = P[(long)d * V + v]; np += x * x;
                float y = T[(long)d * V + v]; nt += y * y;
            }
        }
        pP[dl][pix] = np; pT[dl][pix] = nt;
        __syncthreads();
        if (t < PIXB && b * PIXB + t < V) {
            float sp = 0.f, st = 0.f;
            #pragma unroll
            for (int k = 0; k < 8; ++k) { sp += pP[k][t]; st += pT[k][t]; }
            normP[b * PIXB + t] = sp;
            normT[b * PIXB + t] = st;
        }
    } else {
        if (t < NCLS) {
            // lower_bound of class id t in sorted gt
            int lo = 0, hi = V;
            while (lo < hi) {
                int mid = (lo + hi) >> 1;
                if (gt[mid] < t) lo = mid + 1; else hi = mid;
            }
            ctl->starts[t] = lo;
            ctl->classSum[t] = 0.0f;   // ws is poisoned 0xAA each replay
        }
        if (t == 0) { ctl->starts[NCLS] = V; ctl->done = 0; }
        __syncthreads();
        if (t == 0) {
            int pb = 0;
            for (int c = 0; c < NCLS; ++c) {
                int n = ctl->starts[c + 1] - ctl->starts[c];
                ctl->counts[c] = n;
                int tp = (n + TILE - 1) / TILE;
                ctl->tpc[c] = tp;
                ctl->pairBase[c] = pb;
                pb += tp * tp;
            }
            ctl->pairBase[NCLS] = pb;
        }
    }
}

// ---------------- Kernel 2: balanced flat tile list + fused finalize --------
// dist(i,j) = n_i + n_j - 2<x_i,x_j>  (Gram form, same as reference numerics)
__global__ __launch_bounds__(256) void mmd_kernel(
    const float* __restrict__ P, const float* __restrict__ T,
    int V, int D, Ctl* __restrict__ ctl,
    const float* __restrict__ normP, const float* __restrict__ normT,
    float* __restrict__ out)
{
    __shared__ float sPr[TILE][PAD], sTr[TILE][PAD];
    __shared__ float sPc[TILE][PAD], sTc[TILE][PAD];
    __shared__ float wsum[4];
    __shared__ int isLast;

    const int t  = threadIdx.x;
    const int tx = t & 15;   // cols 2*tx, 2*tx+1
    const int ty = t >> 4;   // rows 2*ty, 2*ty+1
    const int W  = ctl->pairBase[NCLS];
    float* classSum = ctl->classSum;

    const float invs[6] = {-0.25f, -0.1f, -0.05f, -0.025f, -0.0125f, -1.0f/120.0f};

    for (int w = blockIdx.x; w < W; w += gridDim.x) {
        // decode work item -> (class, ti, tj); uniform per block
        int c = 0;
        while (ctl->pairBase[c + 1] <= w) ++c;
        const int local = w - ctl->pairBase[c];
        const int tp    = ctl->tpc[c];
        const int ti    = local / tp;
        const int tj    = local - ti * tp;
        const int n     = ctl->counts[c];
        const int start = ctl->starts[c];
        const int i0    = ti * TILE;
        const int j0    = tj * TILE;

        float dpp[2][2] = {{0.f,0.f},{0.f,0.f}};
        float dtt[2][2] = {{0.f,0.f},{0.f,0.f}};
        float dpt[2][2] = {{0.f,0.f},{0.f,0.f}};

        for (int dc = 0; dc < D; dc += TILE) {
            __syncthreads();   // protect previous chunk's reads / wsum
            // stage: lanes -> consecutive pixels (coalesced global reads)
            for (int k = t; k < TILE * TILE; k += 256) {
                int r = k & (TILE - 1);
                int d = k >> 5;
                int gi = start + min(i0 + r, n - 1);
                int gj = start + min(j0 + r, n - 1);
                long off = (long)(dc + d) * (long)V;
                sPr[r][d] = P[off + gi];
                sTr[r][d] = T[off + gi];
                sPc[r][d] = P[off + gj];
                sTc[r][d] = T[off + gj];
            }
            __syncthreads();

            #pragma unroll
            for (int dg = 0; dg < TILE; dg += 4) {
                float4 pr0 = *(const float4*)&sPr[2*ty    ][dg];
                float4 pr1 = *(const float4*)&sPr[2*ty + 1][dg];
                float4 tr0 = *(const float4*)&sTr[2*ty    ][dg];
                float4 tr1 = *(const float4*)&sTr[2*ty + 1][dg];
                float4 pc0 = *(const float4*)&sPc[2*tx    ][dg];
                float4 pc1 = *(const float4*)&sPc[2*tx + 1][dg];
                float4 tc0 = *(const float4*)&sTc[2*tx    ][dg];
                float4 tc1 = *(const float4*)&sTc[2*tx + 1][dg];

                dpp[0][0] += pr0.x*pc0.x + pr0.y*pc0.y + pr0.z*pc0.z + pr0.w*pc0.w;
                dpp[0][1] += pr0.x*pc1.x + pr0.y*pc1.y + pr0.z*pc1.z + pr0.w*pc1.w;
                dpp[1][0] += pr1.x*pc0.x + pr1.y*pc0.y + pr1.z*pc0.z + pr1.w*pc0.w;
                dpp[1][1] += pr1.x*pc1.x + pr1.y*pc1.y + pr1.z*pc1.z + pr1.w*pc1.w;

                dtt[0][0] += tr0.x*tc0.x + tr0.y*tc0.y + tr0.z*tc0.z + tr0.w*tc0.w;
                dtt[0][1] += tr0.x*tc1.x + tr0.y*tc1.y + tr0.z*tc1.z + tr0.w*tc1.w;
                dtt[1][0] += tr1.x*tc0.x + tr1.y*tc0.y + tr1.z*tc0.z + tr1.w*tc0.w;
                dtt[1][1] += tr1.x*tc1.x + tr1.y*tc1.y + tr1.z*tc1.z + tr1.w*tc1.w;

                dpt[0][0] += pr0.x*tc0.x + pr0.y*tc0.y + pr0.z*tc0.z + pr0.w*tc0.w;
                dpt[0][1] += pr0.x*tc1.x + pr0.y*tc1.y + pr0.z*tc1.z + pr0.w*tc1.w;
                dpt[1][0] += pr1.x*tc0.x + pr1.y*tc0.y + pr1.z*tc0.z + pr1.w*tc0.w;
                dpt[1][1] += pr1.x*tc1.x + pr1.y*tc1.y + pr1.z*tc1.z + pr1.w*tc1.w;
            }
        }

        // epilogue: assemble distances via Gram form, 6-bandwidth RBF sum
        float total = 0.0f;
        #pragma unroll
        for (int a = 0; a < 2; ++a) {
            #pragma unroll
            for (int b2 = 0; b2 < 2; ++b2) {
                int ii = i0 + 2*ty + a;
                int jj = j0 + 2*tx + b2;
                if (ii < n && jj < n) {
                    float nPi = normP[start + ii], nTi = normT[start + ii];
                    float nPj = normP[start + jj], nTj = normT[start + jj];
                    float Dpp = nPi + nPj - 2.0f * dpp[a][b2];
                    float Dtt = nTi + nTj - 2.0f * dtt[a][b2];
                    float Dpt = nPi + nTj - 2.0f * dpt[a][b2];
                    #pragma unroll
                    for (int s = 0; s < 6; ++s) {
                        total += __expf(invs[s] * Dpp)
                               + __expf(invs[s] * Dtt)
                               - 2.0f * __expf(invs[s] * Dpt);
                    }
                }
            }
        }

        // wave shuffle reduce (width 64), then 4 wave leaders via LDS
        #pragma unroll
        for (int off = 32; off > 0; off >>= 1)
            total += __shfl_down(total, off, 64);
        if ((t & 63) == 0) wsum[t >> 6] = total;
        __syncthreads();
        if (t == 0)
            atomicAdd(&classSum[c], wsum[0] + wsum[1] + wsum[2] + wsum[3]);
    }

    // ---- fused finalize: last block to finish computes the scalar loss ----
    __threadfence();   // make our classSum atomics visible before signaling
    if (t == 0) {
        int prev = atomicAdd(&ctl->done, 1);
        isLast = (prev == (int)gridDim.x - 1);
    }
    __syncthreads();
    if (isLast && t == 0) {
        __threadfence();
        float loss = 0.0f;
        int k = 0;
        for (int c = 0; c < NCLS; ++c) {
            int n = ctl->counts[c];
            if (n > 0) {
                ++k;
                float s = __hip_atomic_load(&classSum[c], __ATOMIC_RELAXED,
                                            __HIP_MEMORY_SCOPE_AGENT);
                float fn    = (float)n;
                float denom = fmaxf(2.0f * fn * fn, 1.0f);
                float l     = s / denom;
                if (l > 0.0f) loss += sqrtf(l);
            }
        }
        out[0] = (k > 0) ? (loss / (float)k) : 0.0f;
    }
}

extern "C" void kernel_launch(void* const* d_in, const int* in_sizes, int n_in,
                              void* d_out, int out_size, void* d_ws, size_t ws_size,
                              hipStream_t stream) {
    const float* predict = (const float*)d_in[0];
    const float* target  = (const float*)d_in[1];
    const int*   gt      = (const int*)d_in[2];
    // d_in[3] = ignore_mask: all-True, unused by the reference math.

    const int V = in_sizes[2];        // B*H*W = 4096
    const int D = in_sizes[0] / V;    // C = 128

    Ctl* ctl = (Ctl*)d_ws;
    size_t normOff = (sizeof(Ctl) + 15) & ~(size_t)15;
    float* normP = (float*)((char*)d_ws + normOff);
    float* normT = normP + V;

    int nbNorm = (V + PIXB - 1) / PIXB;
    prep_kernel<<<nbNorm + 1, 256, 0, stream>>>(predict, target, gt, V, D,
                                                ctl, normP, normT, nbNorm);

    mmd_kernel<<<NB, 256, 0, stream>>>(predict, target, V, D, ctl,
                                       normP, normT, (float*)d_out);
}

// Round 4
// 104.888 us; speedup vs baseline: 2.3200x; 2.3200x over previous
//
#include <hip/hip_runtime.h>
#include <math.h>

#define NCLS 16
#define TILE 32
#define PAD  36      // 144 B row pitch: every row 16B-aligned for ds_read_b128
#define NB   2048
#define PIXB 16      // pixels per norm block (16 d-lanes x 16 pixels = 256 threads)

// global float4 loads at 4-byte-aligned addresses (class start is arbitrary)
typedef float vfloat4 __attribute__((ext_vector_type(4), aligned(4)));

struct Ctl {
    int   counts[NCLS];
    int   starts[NCLS + 1];
    int   tpc[NCLS];          // tiles per class dimension = ceil(n/TILE)
    int   pairBase[NCLS + 1]; // prefix sum of tpc^2
    float classSum[NCLS];
};

// ---------------- Kernel 1: norms (pixel x dim parallel) + ctl --------------
// gt is SORTED -> class boundaries via binary search; contiguous segments == classes.
__global__ __launch_bounds__(256) void prep_kernel(
    const float* __restrict__ P, const float* __restrict__ T,
    const int* __restrict__ gt, int V, int D,
    Ctl* __restrict__ ctl,
    float* __restrict__ normP, float* __restrict__ normT,
    int nbNorm) {
    const int b = blockIdx.x;
    const int t = threadIdx.x;
    if (b < nbNorm) {
        __shared__ float pP[16][PIXB + 1], pT[16][PIXB + 1];
        const int pix = t & (PIXB - 1);
        const int dl  = t >> 4;           // 0..15
        const int v   = b * PIXB + pix;
        float np = 0.f, nt = 0.f;
        if (v < V) {
            #pragma unroll 4
            for (int d = dl; d < D; d += 16) {
                float x = P[(long)d * V + v]; np += x * x;
                float y = T[(long)d * V + v]; nt += y * y;
            }
        }
        pP[dl][pix] = np; pT[dl][pix] = nt;
        __syncthreads();
        if (t < PIXB && b * PIXB + t < V) {
            float sp = 0.f, st = 0.f;
            #pragma unroll
            for (int k = 0; k < 16; ++k) { sp += pP[k][t]; st += pT[k][t]; }
            normP[b * PIXB + t] = sp;
            normT[b * PIXB + t] = st;
        }
    } else {
        if (t < NCLS) {
            int lo = 0, hi = V;            // lower_bound of class id t
            while (lo < hi) {
                int mid = (lo + hi) >> 1;
                if (gt[mid] < t) lo = mid + 1; else hi = mid;
            }
            ctl->starts[t] = lo;
            ctl->classSum[t] = 0.0f;       // ws is poisoned 0xAA each replay
        }
        if (t == 0) ctl->starts[NCLS] = V;
        __syncthreads();
        if (t == 0) {
            int pb = 0;
            for (int c = 0; c < NCLS; ++c) {
                int n = ctl->starts[c + 1] - ctl->starts[c];
                ctl->counts[c] = n;
                int tp = (n + TILE - 1) / TILE;
                ctl->tpc[c] = tp;
                ctl->pairBase[c] = pb;
                pb += tp * tp;
            }
            ctl->pairBase[NCLS] = pb;
        }
    }
}

// ---------------- Kernel 2: balanced flat list of 32x32 pair tiles ----------
// dist(i,j) = n_i + n_j - 2<x_i,x_j>  (Gram form, matches reference numerics)
__global__ __launch_bounds__(256) void mmd_kernel(
    const float* __restrict__ P, const float* __restrict__ T,
    int V, int D, const Ctl* __restrict__ ctl,
    const float* __restrict__ normP, const float* __restrict__ normT,
    float* __restrict__ classSum)
{
    __shared__ float sPr[TILE][PAD], sTr[TILE][PAD];
    __shared__ float sPc[TILE][PAD], sTc[TILE][PAD];
    __shared__ float wsum[4];

    const int t  = threadIdx.x;
    const int tx = t & 15;   // cols tx, tx+16  (banks (4tx+dg)%32 -> 2-way, free)
    const int ty = t >> 4;   // rows ty, ty+16
    const int W  = ctl->pairBase[NCLS];

    // staging decode: bijection t -> (d, r4); per-wave d spans 16 values and
    // r4 in {0,4,8,12}(+16) so LDS write banks are 2-way max (free).
    const int sd  = (t >> 2) & 31;
    const int sr4 = ((t & 3) << 2) | ((t >> 7) << 4);

    const float invs[6] = {-0.25f, -0.1f, -0.05f, -0.025f, -0.0125f, -1.0f/120.0f};

    for (int w = blockIdx.x; w < W; w += gridDim.x) {
        int c = 0;
        while (ctl->pairBase[c + 1] <= w) ++c;
        const int local = w - ctl->pairBase[c];
        const int tp    = ctl->tpc[c];
        const int ti    = local / tp;
        const int tj    = local - ti * tp;
        const int n     = ctl->counts[c];
        const int start = ctl->starts[c];
        const int i0    = ti * TILE;
        const int j0    = tj * TILE;

        float dpp[2][2] = {{0.f,0.f},{0.f,0.f}};
        float dtt[2][2] = {{0.f,0.f},{0.f,0.f}};
        float dpt[2][2] = {{0.f,0.f},{0.f,0.f}};

        for (int dc = 0; dc < D; dc += TILE) {
            __syncthreads();   // previous chunk's reads (and wsum) complete
            {
                const long off   = (long)(dc + sd) * (long)V + start;
                const int  ibase = i0 + sr4;
                const int  jbase = j0 + sr4;
                vfloat4 vPr, vTr, vPc, vTc;
                if (ibase + 3 < n) {
                    vPr = *(const vfloat4*)&P[off + ibase];
                    vTr = *(const vfloat4*)&T[off + ibase];
                } else {
                    int a0 = min(ibase, n-1), a1 = min(ibase+1, n-1);
                    int a2 = min(ibase+2, n-1), a3 = min(ibase+3, n-1);
                    vPr = (vfloat4){P[off+a0], P[off+a1], P[off+a2], P[off+a3]};
                    vTr = (vfloat4){T[off+a0], T[off+a1], T[off+a2], T[off+a3]};
                }
                if (jbase + 3 < n) {
                    vPc = *(const vfloat4*)&P[off + jbase];
                    vTc = *(const vfloat4*)&T[off + jbase];
                } else {
                    int a0 = min(jbase, n-1), a1 = min(jbase+1, n-1);
                    int a2 = min(jbase+2, n-1), a3 = min(jbase+3, n-1);
                    vPc = (vfloat4){P[off+a0], P[off+a1], P[off+a2], P[off+a3]};
                    vTc = (vfloat4){T[off+a0], T[off+a1], T[off+a2], T[off+a3]};
                }
                #pragma unroll
                for (int k = 0; k < 4; ++k) {
                    sPr[sr4 + k][sd] = vPr[k];
                    sTr[sr4 + k][sd] = vTr[k];
                    sPc[sr4 + k][sd] = vPc[k];
                    sTc[sr4 + k][sd] = vTc[k];
                }
            }
            __syncthreads();

            #pragma unroll
            for (int dg = 0; dg < TILE; dg += 4) {
                float4 pr0 = *(const float4*)&sPr[ty     ][dg];
                float4 pr1 = *(const float4*)&sPr[ty + 16][dg];
                float4 tr0 = *(const float4*)&sTr[ty     ][dg];
                float4 tr1 = *(const float4*)&sTr[ty + 16][dg];
                float4 pc0 = *(const float4*)&sPc[tx     ][dg];
                float4 pc1 = *(const float4*)&sPc[tx + 16][dg];
                float4 tc0 = *(const float4*)&sTc[tx     ][dg];
                float4 tc1 = *(const float4*)&sTc[tx + 16][dg];

                dpp[0][0] += pr0.x*pc0.x + pr0.y*pc0.y + pr0.z*pc0.z + pr0.w*pc0.w;
                dpp[0][1] += pr0.x*pc1.x + pr0.y*pc1.y + pr0.z*pc1.z + pr0.w*pc1.w;
                dpp[1][0] += pr1.x*pc0.x + pr1.y*pc0.y + pr1.z*pc0.z + pr1.w*pc0.w;
                dpp[1][1] += pr1.x*pc1.x + pr1.y*pc1.y + pr1.z*pc1.z + pr1.w*pc1.w;

                dtt[0][0] += tr0.x*tc0.x + tr0.y*tc0.y + tr0.z*tc0.z + tr0.w*tc0.w;
                dtt[0][1] += tr0.x*tc1.x + tr0.y*tc1.y + tr0.z*tc1.z + tr0.w*tc1.w;
                dtt[1][0] += tr1.x*tc0.x + tr1.y*tc0.y + tr1.z*tc0.z + tr1.w*tc0.w;
                dtt[1][1] += tr1.x*tc1.x + tr1.y*tc1.y + tr1.z*tc1.z + tr1.w*tc1.w;

                dpt[0][0] += pr0.x*tc0.x + pr0.y*tc0.y + pr0.z*tc0.z + pr0.w*tc0.w;
                dpt[0][1] += pr0.x*tc1.x + pr0.y*tc1.y + pr0.z*tc1.z + pr0.w*tc1.w;
                dpt[1][0] += pr1.x*tc0.x + pr1.y*tc0.y + pr1.z*tc0.z + pr1.w*tc0.w;
                dpt[1][1] += pr1.x*tc1.x + pr1.y*tc1.y + pr1.z*tc1.z + pr1.w*tc1.w;
            }
        }

        // epilogue: distances via Gram form, 6-bandwidth RBF sum
        float total = 0.0f;
        #pragma unroll
        for (int a = 0; a < 2; ++a) {
            #pragma unroll
            for (int b2 = 0; b2 < 2; ++b2) {
                int ii = i0 + ty + 16*a;
                int jj = j0 + tx + 16*b2;
                if (ii < n && jj < n) {
                    float nPi = normP[start + ii], nTi = normT[start + ii];
                    float nPj = normP[start + jj], nTj = normT[start + jj];
                    float Dpp = nPi + nPj - 2.0f * dpp[a][b2];
                    float Dtt = nTi + nTj - 2.0f * dtt[a][b2];
                    float Dpt = nPi + nTj - 2.0f * dpt[a][b2];
                    #pragma unroll
                    for (int s = 0; s < 6; ++s) {
                        total += __expf(invs[s] * Dpp)
                               + __expf(invs[s] * Dtt)
                               - 2.0f * __expf(invs[s] * Dpt);
                    }
                }
            }
        }

        // wave shuffle reduce (width 64), 4 wave leaders via LDS, 1 atomic
        #pragma unroll
        for (int off = 32; off > 0; off >>= 1)
            total += __shfl_down(total, off, 64);
        if ((t & 63) == 0) wsum[t >> 6] = total;
        __syncthreads();
        if (t == 0)
            atomicAdd(&classSum[c], wsum[0] + wsum[1] + wsum[2] + wsum[3]);
    }
}

// ---------------- Kernel 3: finalize scalar loss ----------------------------
__global__ void finalize_kernel(const int* __restrict__ counts,
                                const float* __restrict__ classSum,
                                float* __restrict__ out) {
    if (threadIdx.x == 0) {
        float loss = 0.0f;
        int k = 0;
        for (int c = 0; c < NCLS; ++c) {
            int n = counts[c];
            if (n > 0) {
                ++k;
                float fn    = (float)n;
                float denom = fmaxf(2.0f * fn * fn, 1.0f);
                float l     = classSum[c] / denom;
                if (l > 0.0f) loss += sqrtf(l);
            }
        }
        out[0] = (k > 0) ? (loss / (float)k) : 0.0f;
    }
}

extern "C" void kernel_launch(void* const* d_in, const int* in_sizes, int n_in,
                              void* d_out, int out_size, void* d_ws, size_t ws_size,
                              hipStream_t stream) {
    const float* predict = (const float*)d_in[0];
    const float* target  = (const float*)d_in[1];
    const int*   gt      = (const int*)d_in[2];
    // d_in[3] = ignore_mask: all-True, unused by the reference math.

    const int V = in_sizes[2];        // B*H*W = 4096
    const int D = in_sizes[0] / V;    // C = 128

    Ctl* ctl = (Ctl*)d_ws;
    size_t normOff = (sizeof(Ctl) + 15) & ~(size_t)15;
    float* normP = (float*)((char*)d_ws + normOff);
    float* normT = normP + V;
    float* classSum = (float*)((char*)d_ws + offsetof(Ctl, classSum));

    int nbNorm = (V + PIXB - 1) / PIXB;
    prep_kernel<<<nbNorm + 1, 256, 0, stream>>>(predict, target, gt, V, D,
                                                ctl, normP, normT, nbNorm);

    mmd_kernel<<<NB, 256, 0, stream>>>(predict, target, V, D, ctl,
                                       normP, normT, classSum);

    finalize_kernel<<<1, 64, 0, stream>>>(ctl->counts, classSum, (float*)d_out);
}